// Round 1
// baseline (546.245 us; speedup 1.0000x reference)
//
#include <hip/hip_runtime.h>

#define D 128
#define HDIM 256
#define NB 8          // batch size (fixed by setup_inputs)
#define EPB 64        // entities per block in score kernel
#define MAXK 64

// ---------------------------------------------------------------------------
// Kernel 1: ph[b][j] = sum_d h[b][d]*W1h[d][j] + sum_d r[b][d]*W1r[d][j] + b1[j]
// Tiny: 8 blocks x 256 threads.
// ---------------------------------------------------------------------------
__global__ __launch_bounds__(HDIM) void ph_kernel(
        const int* __restrict__ head, const int* __restrict__ relation,
        const float* __restrict__ ent_emb, const float* __restrict__ rel_emb,
        const float* __restrict__ W1, const float* __restrict__ b1,
        float* __restrict__ ph) {
    const int b = blockIdx.x;
    const int j = threadIdx.x;
    const long hidx = head[b];
    const long ridx = relation[b];
    const float* hrow = ent_emb + hidx * D;
    const float* rrow = rel_emb + ridx * D;
    float acc = b1[j];
#pragma unroll 4
    for (int d = 0; d < D; ++d)
        acc += hrow[d] * W1[d * HDIM + j];   // hrow[d] is wave-uniform (scalarizes)
#pragma unroll 4
    for (int d = 0; d < D; ++d)
        acc += rrow[d] * W1[(D + d) * HDIM + j];
    ph[b * HDIM + j] = acc;
}

// ---------------------------------------------------------------------------
// Kernel 2: fused pt = ent_emb @ W1t  and  scores[b][e] =
//           sum_h relu(ph[b][h] + pt[e][h]) * W2[h] + b2[0]
// Tile: 64 entities x 256 cols per block; thread owns 8 entities x 8 cols.
// pt tile lives only in registers (acc[8][8]); never hits global memory.
// ---------------------------------------------------------------------------
__global__ __launch_bounds__(256) void score_kernel(
        const float* __restrict__ ent_emb, const float* __restrict__ W1,
        const float* __restrict__ ph, const float* __restrict__ W2,
        const float* __restrict__ b2, float* __restrict__ scores, int E) {
    __shared__ float emb_lds[EPB][D];   // 32 KiB
    const int tid = threadIdx.x;
    const int base_e = blockIdx.x * EPB;

    // Stage 64 entity rows (float4, coalesced). Tail rows padded with 0.
    for (int t = tid; t < EPB * (D / 4); t += 256) {
        const int row = t >> 5;            // 32 float4 per 128-float row
        const int c4 = (t & 31) << 2;
        float4 v = make_float4(0.f, 0.f, 0.f, 0.f);
        if (base_e + row < E)
            v = *(const float4*)(ent_emb + (size_t)(base_e + row) * D + c4);
        *(float4*)(&emb_lds[row][c4]) = v;
    }
    __syncthreads();

    const int jg = tid & 31;   // column-group: cols 8*jg .. 8*jg+7
    const int eg = tid >> 5;   // entity-group: rows 8*eg .. 8*eg+7
    const int j0 = jg << 3;
    const int r0 = eg << 3;

    float acc[8][8];
#pragma unroll
    for (int i = 0; i < 8; ++i)
#pragma unroll
        for (int c = 0; c < 8; ++c) acc[i][c] = 0.f;

    const float* w1t = W1 + 2 * D * HDIM;   // W1t = W1[256:384]
    for (int d0 = 0; d0 < D; d0 += 4) {
        float4 a[8];
#pragma unroll
        for (int i = 0; i < 8; ++i)
            a[i] = *(const float4*)(&emb_lds[r0 + i][d0]);   // broadcast reads
#pragma unroll
        for (int dd = 0; dd < 4; ++dd) {
            const float4 w0 = *(const float4*)(w1t + (d0 + dd) * HDIM + j0);
            const float4 w1v = *(const float4*)(w1t + (d0 + dd) * HDIM + j0 + 4);
#pragma unroll
            for (int i = 0; i < 8; ++i) {
                const float av = (dd == 0) ? a[i].x : (dd == 1) ? a[i].y
                                : (dd == 2) ? a[i].z : a[i].w;
                acc[i][0] += av * w0.x;
                acc[i][1] += av * w0.y;
                acc[i][2] += av * w0.z;
                acc[i][3] += av * w0.w;
                acc[i][4] += av * w1v.x;
                acc[i][5] += av * w1v.y;
                acc[i][6] += av * w1v.z;
                acc[i][7] += av * w1v.w;
            }
        }
    }

    // Epilogue: relu-weighted sum over cols, reduce across the 32 jg lanes.
    const float4 w2a = *(const float4*)(W2 + j0);
    const float4 w2b = *(const float4*)(W2 + j0 + 4);
    const float b2v = b2[0];

#pragma unroll
    for (int b = 0; b < NB; ++b) {
        const float4 pa = *(const float4*)(ph + b * HDIM + j0);
        const float4 pb = *(const float4*)(ph + b * HDIM + j0 + 4);
        float part[8];
#pragma unroll
        for (int i = 0; i < 8; ++i) {
            float s;
            s  = fmaxf(pa.x + acc[i][0], 0.f) * w2a.x;
            s += fmaxf(pa.y + acc[i][1], 0.f) * w2a.y;
            s += fmaxf(pa.z + acc[i][2], 0.f) * w2a.z;
            s += fmaxf(pa.w + acc[i][3], 0.f) * w2a.w;
            s += fmaxf(pb.x + acc[i][4], 0.f) * w2b.x;
            s += fmaxf(pb.y + acc[i][5], 0.f) * w2b.y;
            s += fmaxf(pb.z + acc[i][6], 0.f) * w2b.z;
            s += fmaxf(pb.w + acc[i][7], 0.f) * w2b.w;
            part[i] = s;
        }
        // Reduce over jg = lanes 0..31 within each half-wave (masks <= 16).
#pragma unroll
        for (int m = 1; m <= 16; m <<= 1) {
#pragma unroll
            for (int i = 0; i < 8; ++i)
                part[i] += __shfl_xor(part[i], m, 64);
        }
        if (jg == 0) {
#pragma unroll
            for (int i = 0; i < 8; ++i) {
                const int e = base_e + r0 + i;
                if (e < E) scores[(size_t)b * E + e] = part[i] + b2v;
            }
        }
    }
}

// ---------------------------------------------------------------------------
// Kernel 3: per-row top-k. Key = (ordered_float(v) << 32) | (0xFFFFFFFF - idx)
// so max-key == (max value, ties -> smallest index), matching lax.top_k.
// ---------------------------------------------------------------------------
__device__ __forceinline__ unsigned long long sk_encode(float v, int idx) {
    unsigned u = __float_as_uint(v);
    u = (u & 0x80000000u) ? ~u : (u | 0x80000000u);
    return ((unsigned long long)u << 32) | (unsigned)(0xFFFFFFFFu - (unsigned)idx);
}

__global__ __launch_bounds__(256) void topk_kernel(
        const float* __restrict__ scores, int E, int k,
        float* __restrict__ out_idx, float* __restrict__ out_val) {
    const int b = blockIdx.x;
    const int tid = threadIdx.x;
    const float* row = scores + (size_t)b * E;

    unsigned long long keys[MAXK];
    for (int i = 0; i < k; ++i) keys[i] = 0ull;   // 0 < any real encoded key
    unsigned long long thr = 0ull;                // register-cached keys[k-1]

    for (int e = tid; e < E; e += 256) {
        const unsigned long long key = sk_encode(row[e], e);
        if (key > thr) {
            int pos = k - 1;
            while (pos > 0 && keys[pos - 1] < key) { keys[pos] = keys[pos - 1]; --pos; }
            keys[pos] = key;
            thr = keys[k - 1];
        }
    }

    __shared__ unsigned long long red[256];
    for (int r = 0; r < k; ++r) {
        red[tid] = keys[0];
        __syncthreads();
        for (int s = 128; s > 0; s >>= 1) {
            if (tid < s && red[tid + s] > red[tid]) red[tid] = red[tid + s];
            __syncthreads();
        }
        const unsigned long long best = red[0];
        __syncthreads();
        if (tid == 0) {
            const unsigned u = (unsigned)(best >> 32);
            const float v = (u & 0x80000000u) ? __uint_as_float(u & 0x7FFFFFFFu)
                                              : __uint_as_float(~u);
            const int e = (int)(0xFFFFFFFFu - (unsigned)(best & 0xFFFFFFFFu));
            out_idx[b * k + r] = (float)e;   // harness reads flat float32
            out_val[b * k + r] = v;
        }
        if (keys[0] == best) {   // exactly one owner (keys embed unique index)
            for (int i = 0; i < k - 1; ++i) keys[i] = keys[i + 1];
            keys[k - 1] = 0ull;
        }
    }
}

// ---------------------------------------------------------------------------
extern "C" void kernel_launch(void* const* d_in, const int* in_sizes, int n_in,
                              void* d_out, int out_size, void* d_ws, size_t ws_size,
                              hipStream_t stream) {
    const int*   head     = (const int*)d_in[0];
    const int*   relation = (const int*)d_in[1];
    // d_in[2] is k on device; k is recovered on host from out_size instead.
    const float* ent_emb  = (const float*)d_in[3];
    const float* rel_emb  = (const float*)d_in[4];
    const float* W1       = (const float*)d_in[5];
    const float* b1       = (const float*)d_in[6];
    const float* W2       = (const float*)d_in[7];
    const float* b2       = (const float*)d_in[8];

    const int B = in_sizes[0];          // 8
    const int E = in_sizes[3] / D;      // 50000
    int k = out_size / (2 * B);         // 10
    if (k > MAXK) k = MAXK;

    float* ph     = (float*)d_ws;                       // B*HDIM floats
    float* scores = ph + (size_t)B * HDIM;              // B*E floats (~1.6 MB)
    float* out    = (float*)d_out;

    ph_kernel<<<B, HDIM, 0, stream>>>(head, relation, ent_emb, rel_emb, W1, b1, ph);
    const int nblk = (E + EPB - 1) / EPB;
    score_kernel<<<nblk, 256, 0, stream>>>(ent_emb, W1, ph, W2, b2, scores, E);
    topk_kernel<<<B, 256, 0, stream>>>(scores, E, k, out, out + (size_t)B * k);
}

// Round 2
// 237.468 us; speedup vs baseline: 2.3003x; 2.3003x over previous
//
#include <hip/hip_runtime.h>

#define D 128
#define HDIM 256
#define NB 8          // batch size (fixed by setup_inputs)
#define EPB 64        // entities per block in score kernel
#define TOPK_THREADS 1024
#define TOPK_WAVES (TOPK_THREADS / 64)

// ---------------------------------------------------------------------------
// Kernel 1: ph[b][j] = sum_d h[b][d]*W1h[d][j] + sum_d r[b][d]*W1r[d][j] + b1[j]
// ---------------------------------------------------------------------------
__global__ __launch_bounds__(HDIM) void ph_kernel(
        const int* __restrict__ head, const int* __restrict__ relation,
        const float* __restrict__ ent_emb, const float* __restrict__ rel_emb,
        const float* __restrict__ W1, const float* __restrict__ b1,
        float* __restrict__ ph) {
    const int b = blockIdx.x;
    const int j = threadIdx.x;
    const long hidx = head[b];
    const long ridx = relation[b];
    const float* hrow = ent_emb + hidx * D;
    const float* rrow = rel_emb + ridx * D;
    float acc = b1[j];
#pragma unroll 4
    for (int d = 0; d < D; ++d)
        acc += hrow[d] * W1[d * HDIM + j];
#pragma unroll 4
    for (int d = 0; d < D; ++d)
        acc += rrow[d] * W1[(D + d) * HDIM + j];
    ph[b * HDIM + j] = acc;
}

// ---------------------------------------------------------------------------
// Kernel 2: fused pt = ent_emb @ W1t  and  scores[b][e] =
//           sum_h relu(ph[b][h] + pt[e][h]) * W2[h] + b2[0]
// (unchanged from R1 — topk was the bottleneck; score is next round's target)
// ---------------------------------------------------------------------------
__global__ __launch_bounds__(256) void score_kernel(
        const float* __restrict__ ent_emb, const float* __restrict__ W1,
        const float* __restrict__ ph, const float* __restrict__ W2,
        const float* __restrict__ b2, float* __restrict__ scores, int E) {
    __shared__ float emb_lds[EPB][D];   // 32 KiB
    const int tid = threadIdx.x;
    const int base_e = blockIdx.x * EPB;

    for (int t = tid; t < EPB * (D / 4); t += 256) {
        const int row = t >> 5;
        const int c4 = (t & 31) << 2;
        float4 v = make_float4(0.f, 0.f, 0.f, 0.f);
        if (base_e + row < E)
            v = *(const float4*)(ent_emb + (size_t)(base_e + row) * D + c4);
        *(float4*)(&emb_lds[row][c4]) = v;
    }
    __syncthreads();

    const int jg = tid & 31;
    const int eg = tid >> 5;
    const int j0 = jg << 3;
    const int r0 = eg << 3;

    float acc[8][8];
#pragma unroll
    for (int i = 0; i < 8; ++i)
#pragma unroll
        for (int c = 0; c < 8; ++c) acc[i][c] = 0.f;

    const float* w1t = W1 + 2 * D * HDIM;
    for (int d0 = 0; d0 < D; d0 += 4) {
        float4 a[8];
#pragma unroll
        for (int i = 0; i < 8; ++i)
            a[i] = *(const float4*)(&emb_lds[r0 + i][d0]);
#pragma unroll
        for (int dd = 0; dd < 4; ++dd) {
            const float4 w0 = *(const float4*)(w1t + (d0 + dd) * HDIM + j0);
            const float4 w1v = *(const float4*)(w1t + (d0 + dd) * HDIM + j0 + 4);
#pragma unroll
            for (int i = 0; i < 8; ++i) {
                const float av = (dd == 0) ? a[i].x : (dd == 1) ? a[i].y
                                : (dd == 2) ? a[i].z : a[i].w;
                acc[i][0] += av * w0.x;
                acc[i][1] += av * w0.y;
                acc[i][2] += av * w0.z;
                acc[i][3] += av * w0.w;
                acc[i][4] += av * w1v.x;
                acc[i][5] += av * w1v.y;
                acc[i][6] += av * w1v.z;
                acc[i][7] += av * w1v.w;
            }
        }
    }

    const float4 w2a = *(const float4*)(W2 + j0);
    const float4 w2b = *(const float4*)(W2 + j0 + 4);
    const float b2v = b2[0];

#pragma unroll
    for (int b = 0; b < NB; ++b) {
        const float4 pa = *(const float4*)(ph + b * HDIM + j0);
        const float4 pb = *(const float4*)(ph + b * HDIM + j0 + 4);
        float part[8];
#pragma unroll
        for (int i = 0; i < 8; ++i) {
            float s;
            s  = fmaxf(pa.x + acc[i][0], 0.f) * w2a.x;
            s += fmaxf(pa.y + acc[i][1], 0.f) * w2a.y;
            s += fmaxf(pa.z + acc[i][2], 0.f) * w2a.z;
            s += fmaxf(pa.w + acc[i][3], 0.f) * w2a.w;
            s += fmaxf(pb.x + acc[i][4], 0.f) * w2b.x;
            s += fmaxf(pb.y + acc[i][5], 0.f) * w2b.y;
            s += fmaxf(pb.z + acc[i][6], 0.f) * w2b.z;
            s += fmaxf(pb.w + acc[i][7], 0.f) * w2b.w;
            part[i] = s;
        }
#pragma unroll
        for (int m = 1; m <= 16; m <<= 1) {
#pragma unroll
            for (int i = 0; i < 8; ++i)
                part[i] += __shfl_xor(part[i], m, 64);
        }
        if (jg == 0) {
#pragma unroll
            for (int i = 0; i < 8; ++i) {
                const int e = base_e + r0 + i;
                if (e < E) scores[(size_t)b * E + e] = part[i] + b2v;
            }
        }
    }
}

// ---------------------------------------------------------------------------
// Kernel 3: per-row top-k, static-index registers only (no scratch).
// Key = (ordered_float(v) << 32) | (0xFFFFFFFF - idx): max-key == max value,
// ties -> smallest index (lax.top_k semantics). Keys are globally unique.
// ---------------------------------------------------------------------------
__device__ __forceinline__ unsigned long long sk_encode(float v, int idx) {
    unsigned u = __float_as_uint(v);
    u = (u & 0x80000000u) ? ~u : (u | 0x80000000u);
    return ((unsigned long long)u << 32) | (unsigned)(0xFFFFFFFFu - (unsigned)idx);
}

__device__ __forceinline__ unsigned long long wave_max64(unsigned long long m) {
#pragma unroll
    for (int s = 32; s > 0; s >>= 1) {
        const unsigned long long o = __shfl_xor(m, s, 64);
        if (o > m) m = o;
    }
    return m;
}

template <int K>
__global__ __launch_bounds__(TOPK_THREADS) void topk_kernel(
        const float* __restrict__ scores, int E, int k,
        float* __restrict__ out_idx, float* __restrict__ out_val) {
    const int b = blockIdx.x;
    const int tid = threadIdx.x;
    const int lane = tid & 63;
    const int wave = tid >> 6;
    const float* row = scores + (size_t)b * E;

    // Per-thread top-K. All indices static -> stays in VGPRs.
    unsigned long long keys[K];
#pragma unroll
    for (int i = 0; i < K; ++i) keys[i] = 0ull;

    for (int e = tid; e < E; e += TOPK_THREADS) {
        unsigned long long key = sk_encode(row[e], e);
        if (key > keys[K - 1]) {
            // sorted-insert via compare-swap chain (static indices only)
#pragma unroll
            for (int j = 0; j < K; ++j) {
                const bool gt = key > keys[j];
                const unsigned long long mx = gt ? key : keys[j];
                key = gt ? keys[j] : key;
                keys[j] = mx;
            }
        }
    }

    // Per-wave: k rounds of wave-wide max + pop (keys unique -> one owner).
    __shared__ unsigned long long cand[TOPK_WAVES * 16];  // k <= 16
    for (int r = 0; r < k; ++r) {
        const unsigned long long m = wave_max64(keys[0]);
        if (keys[0] == m) {
#pragma unroll
            for (int j = 0; j < K - 1; ++j) keys[j] = keys[j + 1];
            keys[K - 1] = 0ull;
        }
        if (lane == 0) cand[wave * k + r] = m;   // r uniform -> fine
    }
    __syncthreads();

    // Wave 0 merges TOPK_WAVES*k candidates (<= 256) and writes output.
    if (wave == 0) {
        const int ncand = TOPK_WAVES * k;
        unsigned long long lk[K];
#pragma unroll
        for (int i = 0; i < K; ++i) lk[i] = 0ull;
        for (int c = lane; c < ncand; c += 64) {
            unsigned long long key = cand[c];
            if (key > lk[K - 1]) {
#pragma unroll
                for (int j = 0; j < K; ++j) {
                    const bool gt = key > lk[j];
                    const unsigned long long mx = gt ? key : lk[j];
                    key = gt ? lk[j] : key;
                    lk[j] = mx;
                }
            }
        }
        for (int r = 0; r < k; ++r) {
            const unsigned long long m = wave_max64(lk[0]);
            if (lk[0] == m) {
#pragma unroll
                for (int j = 0; j < K - 1; ++j) lk[j] = lk[j + 1];
                lk[K - 1] = 0ull;
            }
            if (lane == 0) {
                const unsigned u = (unsigned)(m >> 32);
                const float v = (u & 0x80000000u) ? __uint_as_float(u & 0x7FFFFFFFu)
                                                  : __uint_as_float(~u);
                const int e = (int)(0xFFFFFFFFu - (unsigned)(m & 0xFFFFFFFFu));
                out_idx[b * k + r] = (float)e;
                out_val[b * k + r] = v;
            }
        }
    }
}

// ---------------------------------------------------------------------------
extern "C" void kernel_launch(void* const* d_in, const int* in_sizes, int n_in,
                              void* d_out, int out_size, void* d_ws, size_t ws_size,
                              hipStream_t stream) {
    const int*   head     = (const int*)d_in[0];
    const int*   relation = (const int*)d_in[1];
    const float* ent_emb  = (const float*)d_in[3];
    const float* rel_emb  = (const float*)d_in[4];
    const float* W1       = (const float*)d_in[5];
    const float* b1       = (const float*)d_in[6];
    const float* W2       = (const float*)d_in[7];
    const float* b2       = (const float*)d_in[8];

    const int B = in_sizes[0];          // 8
    const int E = in_sizes[3] / D;      // 50000
    int k = out_size / (2 * B);         // 10
    if (k > 16) k = 16;                 // problem ships k=10; cap for K=16 path

    float* ph     = (float*)d_ws;                       // B*HDIM floats
    float* scores = ph + (size_t)B * HDIM;              // B*E floats (~1.6 MB)
    float* out    = (float*)d_out;

    ph_kernel<<<B, HDIM, 0, stream>>>(head, relation, ent_emb, rel_emb, W1, b1, ph);
    const int nblk = (E + EPB - 1) / EPB;
    score_kernel<<<nblk, 256, 0, stream>>>(ent_emb, W1, ph, W2, b2, scores, E);
    topk_kernel<16><<<B, TOPK_THREADS, 0, stream>>>(scores, E, k, out, out + (size_t)B * k);
}

// Round 3
// 186.018 us; speedup vs baseline: 2.9365x; 1.2766x over previous
//
#include <hip/hip_runtime.h>

#define D 128
#define HDIM 256
#define NB 8            // batch size (fixed by setup_inputs)
#define EPB 64          // entities per block in score kernel
#define NSHARD 8        // topk shards per row
#define CPS 16          // candidates per shard
#define NCAND (NSHARD * CPS)   // 128 candidates per row

typedef short bf16x8 __attribute__((ext_vector_type(8)));
typedef float f32x4 __attribute__((ext_vector_type(4)));

__device__ __forceinline__ unsigned short f2bf(float x) {
    unsigned u = __float_as_uint(x);
    unsigned r = u + 0x7FFF + ((u >> 16) & 1);   // RNE (finite data)
    return (unsigned short)(r >> 16);
}

// key = (ordered_float << 32) | (0xFFFFFFFF - idx): max == (max val, min idx)
__device__ __forceinline__ unsigned long long sk_encode(float v, int idx) {
    unsigned u = __float_as_uint(v);
    u = (u & 0x80000000u) ? ~u : (u | 0x80000000u);
    return ((unsigned long long)u << 32) | (unsigned)(0xFFFFFFFFu - (unsigned)idx);
}
__device__ __forceinline__ float sk_val(unsigned long long key) {
    const unsigned u = (unsigned)(key >> 32);
    return (u & 0x80000000u) ? __uint_as_float(u & 0x7FFFFFFFu) : __uint_as_float(~u);
}
__device__ __forceinline__ int sk_idx(unsigned long long key) {
    return (int)(0xFFFFFFFFu - (unsigned)(key & 0xFFFFFFFFu));
}
__device__ __forceinline__ unsigned long long wave_max64(unsigned long long m) {
#pragma unroll
    for (int s = 32; s > 0; s >>= 1) {
        const unsigned long long o = __shfl_xor(m, s, 64);
        if (o > m) m = o;
    }
    return m;
}

// ---------------------------------------------------------------------------
// K1: blocks 0..7 -> ph[b][j] (fp32, exact);  block 8 -> w1tt = bf16(W1t^T)
// w1tt[n][k] = bf16(W1[(2D+k)*HDIM + n]),  n in [0,256), k in [0,128)
// ---------------------------------------------------------------------------
__global__ __launch_bounds__(HDIM) void prep_kernel(
        const int* __restrict__ head, const int* __restrict__ relation,
        const float* __restrict__ ent_emb, const float* __restrict__ rel_emb,
        const float* __restrict__ W1, const float* __restrict__ b1,
        float* __restrict__ ph, unsigned short* __restrict__ w1tt) {
    const int tid = threadIdx.x;
    if (blockIdx.x < NB) {
        const int b = blockIdx.x;
        const long hidx = head[b];
        const long ridx = relation[b];
        const float* hrow = ent_emb + hidx * D;
        const float* rrow = rel_emb + ridx * D;
        float acc = b1[tid];
#pragma unroll 8
        for (int d = 0; d < D; ++d)
            acc += hrow[d] * W1[d * HDIM + tid];
#pragma unroll 8
        for (int d = 0; d < D; ++d)
            acc += rrow[d] * W1[(D + d) * HDIM + tid];
        ph[b * HDIM + tid] = acc;
    } else {
        // transpose W1t (k-major [128][256]) -> w1tt (n-major [256][128]) bf16
        const int n = tid;
        const float* w1t = W1 + 2 * D * HDIM;
        for (int k0 = 0; k0 < D; k0 += 8) {
            unsigned short pk[8];
#pragma unroll
            for (int j = 0; j < 8; ++j)
                pk[j] = f2bf(w1t[(k0 + j) * HDIM + n]);   // coalesced across n
            *(ushort4*)(w1tt + n * D + k0)     = make_ushort4(pk[0], pk[1], pk[2], pk[3]);
            *(ushort4*)(w1tt + n * D + k0 + 4) = make_ushort4(pk[4], pk[5], pk[6], pk[7]);
        }
    }
}

// ---------------------------------------------------------------------------
// K2: MFMA score. Per block: 64 entities x all 256 cols, K=128.
// LDS: ent tile bf16 [64][136] + W1t^T half [128][136] + ph + W2 = 60 KB.
// mfma_f32_16x16x32_bf16: A[m=lane&15][k=(lane>>4)*8+j]; B[k][n=lane&15];
// C: col=lane&15, row=(lane>>4)*4+reg.
// ---------------------------------------------------------------------------
#define LPAD 136   // row stride (ushorts): 272 B, 16B-aligned, 2-way banks (free)

__global__ __launch_bounds__(256) void score_kernel(
        const float* __restrict__ ent_emb, const unsigned short* __restrict__ w1tt,
        const float* __restrict__ ph, const float* __restrict__ W2,
        float* __restrict__ scores, int E) {
    __shared__ __align__(16) unsigned short entL[EPB][LPAD];   // 17.0 KB
    __shared__ __align__(16) unsigned short wL[128][LPAD];     // 34.0 KB
    __shared__ float phL[NB][HDIM];                            //  8 KB
    __shared__ float w2L[HDIM];                                //  1 KB

    const int tid = threadIdx.x;
    const int base_e = blockIdx.x * EPB;
    const int lane = tid & 63;
    const int wave = tid >> 6;
    const int lm = lane & 15;      // MFMA row/col-within-tile index
    const int q  = lane >> 4;      // quad
    const int m0 = wave * 16;      // this wave's entity offset in tile

    // ---- stage ent tile (fp32 -> bf16), ph, W2, and wL half 0 ----
    for (int t = tid; t < EPB * (D / 4); t += 256) {
        const int row = t >> 5, c4 = (t & 31) << 2;
        float4 v = make_float4(0.f, 0.f, 0.f, 0.f);
        if (base_e + row < E)
            v = *(const float4*)(ent_emb + (size_t)(base_e + row) * D + c4);
        *(ushort4*)(&entL[row][c4]) =
            make_ushort4(f2bf(v.x), f2bf(v.y), f2bf(v.z), f2bf(v.w));
    }
    for (int t = tid; t < NB * HDIM / 4; t += 256)
        *(float4*)(&phL[0][0] + t * 4) = *(const float4*)(ph + t * 4);
    if (tid < HDIM / 4)
        *(float4*)(w2L + tid * 4) = *(const float4*)(W2 + tid * 4);
    for (int t = tid; t < 128 * (D / 8); t += 256) {     // half 0 of w1tt
        const int row = t >> 4, seg = t & 15;
        *(uint4*)(&wL[row][seg * 8]) = *(const uint4*)(w1tt + (size_t)row * D + seg * 8);
    }
    __syncthreads();

    float spart[NB * 4];
#pragma unroll
    for (int i = 0; i < NB * 4; ++i) spart[i] = 0.f;

#pragma unroll
    for (int p = 0; p < 2; ++p) {
        if (p == 1) {
            __syncthreads();   // all reads of wL half0 done
            for (int t = tid; t < 128 * (D / 8); t += 256) {
                const int row = t >> 4, seg = t & 15;
                *(uint4*)(&wL[row][seg * 8]) =
                    *(const uint4*)(w1tt + (size_t)(128 + row) * D + seg * 8);
            }
            __syncthreads();
        }
        f32x4 acc[8];
#pragma unroll
        for (int nt = 0; nt < 8; ++nt) acc[nt] = (f32x4){0.f, 0.f, 0.f, 0.f};
#pragma unroll
        for (int kk = 0; kk < 4; ++kk) {
            const bf16x8 aF = *(const bf16x8*)(&entL[m0 + lm][kk * 32 + q * 8]);
#pragma unroll
            for (int nt = 0; nt < 8; ++nt) {
                const bf16x8 bF = *(const bf16x8*)(&wL[nt * 16 + lm][kk * 32 + q * 8]);
                acc[nt] = __builtin_amdgcn_mfma_f32_16x16x32_bf16(aF, bF, acc[nt], 0, 0, 0);
            }
        }
        // fused epilogue: spart[b][r] += relu(ph + pt) * W2
#pragma unroll
        for (int nt = 0; nt < 8; ++nt) {
            const int h = p * 128 + nt * 16 + lm;
            const float w2v = w2L[h];
#pragma unroll
            for (int b = 0; b < NB; ++b) {
                const float phv = phL[b][h];
#pragma unroll
                for (int r = 0; r < 4; ++r)
                    spart[b * 4 + r] += fmaxf(phv + acc[nt][r], 0.f) * w2v;
            }
        }
    }

    // reduce over the 16 lanes of each quad (bits 0..3)
#pragma unroll
    for (int m = 1; m <= 8; m <<= 1) {
#pragma unroll
        for (int i = 0; i < NB * 4; ++i)
            spart[i] += __shfl_xor(spart[i], m, 64);
    }
    if (lm == 0) {
#pragma unroll
        for (int r = 0; r < 4; ++r) {
            const int e = base_e + m0 + q * 4 + r;
            if (e < E) {
#pragma unroll
                for (int b = 0; b < NB; ++b)
                    scores[(size_t)b * E + e] = spart[b * 4 + r];
            }
        }
    }
}

// ---------------------------------------------------------------------------
// K3: shard top-16 (bf16-approx scores). 64 blocks = 8 rows x 8 shards.
// Per-thread K=16 registers provably retain every row-top-16 element.
// ---------------------------------------------------------------------------
__global__ __launch_bounds__(256) void topk_shard_kernel(
        const float* __restrict__ scores, int E,
        unsigned long long* __restrict__ cand) {
    const int b = blockIdx.x >> 3;
    const int s = blockIdx.x & 7;
    const int tid = threadIdx.x;
    const int lane = tid & 63;
    const int wave = tid >> 6;
    const int shard = (E + NSHARD - 1) / NSHARD;
    const int start = s * shard;
    const int end = min(E, start + shard);
    const float* row = scores + (size_t)b * E;

    unsigned long long keys[CPS];
#pragma unroll
    for (int i = 0; i < CPS; ++i) keys[i] = 0ull;

    for (int e = start + tid; e < end; e += 256) {
        unsigned long long key = sk_encode(row[e], e);
        if (key > keys[CPS - 1]) {
#pragma unroll
            for (int j = 0; j < CPS; ++j) {
                const bool gt = key > keys[j];
                const unsigned long long mx = gt ? key : keys[j];
                key = gt ? keys[j] : key;
                keys[j] = mx;
            }
        }
    }

    __shared__ unsigned long long cl[4 * CPS];   // 64 entries
    for (int r = 0; r < CPS; ++r) {
        const unsigned long long m = wave_max64(keys[0]);
        if (keys[0] == m) {
#pragma unroll
            for (int j = 0; j < CPS - 1; ++j) keys[j] = keys[j + 1];
            keys[CPS - 1] = 0ull;
        }
        if (lane == 0) cl[wave * CPS + r] = m;
    }
    __syncthreads();
    if (wave == 0) {
        unsigned long long v = cl[lane];          // exactly 64 candidates
        for (int r = 0; r < CPS; ++r) {
            const unsigned long long m = wave_max64(v);
            if (v == m) v = 0ull;
            if (lane == 0) cand[(size_t)(b * NSHARD + s) * CPS + r] = m;
        }
    }
}

// ---------------------------------------------------------------------------
// K4: exact fp32 rescore of the 128 candidates per row. 1024 blocks.
// ---------------------------------------------------------------------------
__global__ __launch_bounds__(HDIM) void rescore_kernel(
        const unsigned long long* __restrict__ cand,
        const float* __restrict__ ent_emb, const float* __restrict__ W1,
        const float* __restrict__ ph, const float* __restrict__ W2,
        const float* __restrict__ b2, float* __restrict__ exact) {
    const int b = blockIdx.x >> 7;
    const int ci = blockIdx.x & 127;
    const int tid = threadIdx.x;
    const int lane = tid & 63;
    const int wave = tid >> 6;
    const int e = sk_idx(cand[(size_t)b * NCAND + ci]);

    __shared__ float entR[D];
    if (tid < D / 4)
        *(float4*)(entR + tid * 4) = *(const float4*)(ent_emb + (size_t)e * D + tid * 4);
    __syncthreads();

    const float* w1t = W1 + 2 * D * HDIM;
    float acc = 0.f;
#pragma unroll 8
    for (int d = 0; d < D; ++d)
        acc += entR[d] * w1t[d * HDIM + tid];   // coalesced across tid
    float s = fmaxf(acc + ph[b * HDIM + tid], 0.f) * W2[tid];

#pragma unroll
    for (int m = 1; m <= 32; m <<= 1) s += __shfl_xor(s, m, 64);
    __shared__ float red[4];
    if (lane == 0) red[wave] = s;
    __syncthreads();
    if (tid == 0)
        exact[(size_t)b * NCAND + ci] = red[0] + red[1] + red[2] + red[3] + b2[0];
}

// ---------------------------------------------------------------------------
// K5: final top-k per row from 128 exactly-scored candidates. 1 block.
// ---------------------------------------------------------------------------
__global__ __launch_bounds__(NB * 64) void final_kernel(
        const unsigned long long* __restrict__ cand,
        const float* __restrict__ exact, int k,
        float* __restrict__ out_idx, float* __restrict__ out_val) {
    const int b = threadIdx.x >> 6;     // wave = row
    const int lane = threadIdx.x & 63;

    unsigned long long k0, k1;
    {
        const int c0 = lane, c1 = lane + 64;
        const unsigned long long a = sk_encode(exact[b * NCAND + c0],
                                               sk_idx(cand[b * NCAND + c0]));
        const unsigned long long bb = sk_encode(exact[b * NCAND + c1],
                                                sk_idx(cand[b * NCAND + c1]));
        k0 = a > bb ? a : bb;
        k1 = a > bb ? bb : a;
    }
    for (int r = 0; r < k; ++r) {
        const unsigned long long m = wave_max64(k0);
        if (k0 == m) { k0 = k1; k1 = 0ull; }
        if (lane == 0) {
            out_idx[b * k + r] = (float)sk_idx(m);
            out_val[b * k + r] = sk_val(m);
        }
    }
}

// ---------------------------------------------------------------------------
extern "C" void kernel_launch(void* const* d_in, const int* in_sizes, int n_in,
                              void* d_out, int out_size, void* d_ws, size_t ws_size,
                              hipStream_t stream) {
    const int*   head     = (const int*)d_in[0];
    const int*   relation = (const int*)d_in[1];
    const float* ent_emb  = (const float*)d_in[3];
    const float* rel_emb  = (const float*)d_in[4];
    const float* W1       = (const float*)d_in[5];
    const float* b1       = (const float*)d_in[6];
    const float* W2       = (const float*)d_in[7];
    const float* b2       = (const float*)d_in[8];

    const int B = in_sizes[0];          // 8
    const int E = in_sizes[3] / D;      // 50000
    int k = out_size / (2 * B);         // 10
    if (k > CPS) k = CPS;

    char* ws = (char*)d_ws;
    unsigned long long* cand  = (unsigned long long*)ws;            //  8 KB
    float*          ph        = (float*)(ws + 8192);                //  8 KB
    unsigned short* w1tt      = (unsigned short*)(ws + 16384);      // 64 KB
    float*          exact     = (float*)(ws + 81920);               //  4 KB
    float*          scores    = (float*)(ws + 86016);               // 1.6 MB
    float*          out       = (float*)d_out;

    prep_kernel<<<NB + 1, HDIM, 0, stream>>>(head, relation, ent_emb, rel_emb,
                                             W1, b1, ph, w1tt);
    const int nblk = (E + EPB - 1) / EPB;
    score_kernel<<<nblk, 256, 0, stream>>>(ent_emb, w1tt, ph, W2, scores, E);
    topk_shard_kernel<<<NB * NSHARD, 256, 0, stream>>>(scores, E, cand);
    rescore_kernel<<<NB * NCAND, HDIM, 0, stream>>>(cand, ent_emb, W1, ph, W2, b2, exact);
    final_kernel<<<1, NB * 64, 0, stream>>>(cand, exact, k, out, out + (size_t)B * k);
}

// Round 4
// 173.612 us; speedup vs baseline: 3.1464x; 1.0715x over previous
//
#include <hip/hip_runtime.h>

#define D 128
#define HDIM 256
#define NB 8            // batch size (fixed by setup_inputs)
#define EPB 64          // entities per block in score kernel
#define NSHARD 8        // topk shards per row
#define CPS 16          // candidates per shard
#define NCAND (NSHARD * CPS)   // 128 candidates per row
#define RCPB 4          // candidates per rescore block

typedef short bf16x8 __attribute__((ext_vector_type(8)));
typedef float f32x4 __attribute__((ext_vector_type(4)));

__device__ __forceinline__ unsigned short f2bf(float x) {
    unsigned u = __float_as_uint(x);
    unsigned r = u + 0x7FFF + ((u >> 16) & 1);   // RNE (finite data)
    return (unsigned short)(r >> 16);
}
__device__ __forceinline__ bf16x8 pack_bf8(float4 u, float4 v) {
    union { bf16x8 v8; unsigned short s[8]; } r;
    r.s[0] = f2bf(u.x); r.s[1] = f2bf(u.y); r.s[2] = f2bf(u.z); r.s[3] = f2bf(u.w);
    r.s[4] = f2bf(v.x); r.s[5] = f2bf(v.y); r.s[6] = f2bf(v.z); r.s[7] = f2bf(v.w);
    return r.v8;
}

// key = (ordered_float << 32) | (0xFFFFFFFF - idx): max == (max val, min idx)
__device__ __forceinline__ unsigned long long sk_encode(float v, int idx) {
    unsigned u = __float_as_uint(v);
    u = (u & 0x80000000u) ? ~u : (u | 0x80000000u);
    return ((unsigned long long)u << 32) | (unsigned)(0xFFFFFFFFu - (unsigned)idx);
}
__device__ __forceinline__ float sk_val(unsigned long long key) {
    const unsigned u = (unsigned)(key >> 32);
    return (u & 0x80000000u) ? __uint_as_float(u & 0x7FFFFFFFu) : __uint_as_float(~u);
}
__device__ __forceinline__ int sk_idx(unsigned long long key) {
    return (int)(0xFFFFFFFFu - (unsigned)(key & 0xFFFFFFFFu));
}
__device__ __forceinline__ unsigned long long wave_max64(unsigned long long m) {
#pragma unroll
    for (int s = 32; s > 0; s >>= 1) {
        const unsigned long long o = __shfl_xor(m, s, 64);
        if (o > m) m = o;
    }
    return m;
}

// ---------------------------------------------------------------------------
// K1: blocks 0..7 -> ph[b][j] (fp32, exact)
//     blocks 8..15 -> w1tt = bf16(W1t^T), each block does 16 k-columns
// ---------------------------------------------------------------------------
__global__ __launch_bounds__(HDIM) void prep_kernel(
        const int* __restrict__ head, const int* __restrict__ relation,
        const float* __restrict__ ent_emb, const float* __restrict__ rel_emb,
        const float* __restrict__ W1, const float* __restrict__ b1,
        float* __restrict__ ph, unsigned short* __restrict__ w1tt) {
    const int tid = threadIdx.x;
    if (blockIdx.x < NB) {
        const int b = blockIdx.x;
        const long hidx = head[b];
        const long ridx = relation[b];
        const float* hrow = ent_emb + hidx * D;
        const float* rrow = rel_emb + ridx * D;
        float acc = b1[tid];
#pragma unroll 8
        for (int d = 0; d < D; ++d)
            acc += hrow[d] * W1[d * HDIM + tid];
#pragma unroll 8
        for (int d = 0; d < D; ++d)
            acc += rrow[d] * W1[(D + d) * HDIM + tid];
        ph[b * HDIM + tid] = acc;
    } else {
        // transpose W1t (k-major [128][256]) -> w1tt (n-major [256][128]) bf16
        const int n = tid;
        const int k0 = (blockIdx.x - NB) * 16;
        const float* w1t = W1 + 2 * D * HDIM;
        unsigned short pk[16];
#pragma unroll
        for (int j = 0; j < 16; ++j)
            pk[j] = f2bf(w1t[(k0 + j) * HDIM + n]);   // coalesced across n
#pragma unroll
        for (int j = 0; j < 16; j += 4)
            *(ushort4*)(w1tt + n * D + k0 + j) =
                make_ushort4(pk[j], pk[j + 1], pk[j + 2], pk[j + 3]);
    }
}

// ---------------------------------------------------------------------------
// K2: MFMA score, no staging LDS. Per block: 64 entities x 256 cols, K=128.
// A-fragments loaded directly from ent_emb (each row read once, by one wave);
// B-fragments loaded directly from w1tt (64 KB, L2-hot; each wave-load is
// 16 fully-used 64B lines). LDS only for phT[h][b] + W2 (9 KB).
// mfma_f32_16x16x32_bf16: A[m=lane&15][k=(lane>>4)*8+j]; B[k][n=lane&15];
// C: col(n)=lane&15, row(m)=(lane>>4)*4+reg.
// ---------------------------------------------------------------------------
__global__ __launch_bounds__(256) void score_kernel(
        const float* __restrict__ ent_emb, const unsigned short* __restrict__ w1tt,
        const float* __restrict__ ph, const float* __restrict__ W2,
        float* __restrict__ scores, int E) {
    __shared__ float phT[HDIM][NB];   // [h][b], 8 KB
    __shared__ float w2L[HDIM];       // 1 KB

    const int tid = threadIdx.x;
    const int lane = tid & 63;
    const int wave = tid >> 6;
    const int lm = lane & 15;
    const int q = lane >> 4;
    const int base_e = blockIdx.x * EPB;
    const int m0 = wave * 16;

    // stage phT (transposed) + w2
    w2L[tid] = W2[tid];
#pragma unroll
    for (int b = 0; b < NB; ++b) phT[tid][b] = ph[b * HDIM + tid];

    // A fragments direct from global (no barrier dependency)
    const int erow = base_e + m0 + lm;
    const float* arow = ent_emb + (size_t)min(erow, E - 1) * D;
    bf16x8 aF[4];
#pragma unroll
    for (int kk = 0; kk < 4; ++kk) {
        const float4 u = *(const float4*)(arow + kk * 32 + q * 8);
        const float4 v = *(const float4*)(arow + kk * 32 + q * 8 + 4);
        aF[kk] = pack_bf8(u, v);
    }
    __syncthreads();   // phT/w2L ready

    float spart[NB * 4];
#pragma unroll
    for (int i = 0; i < NB * 4; ++i) spart[i] = 0.f;

#pragma unroll
    for (int p = 0; p < 2; ++p) {
#pragma unroll
        for (int nt = 0; nt < 8; ++nt) {
            const int h = p * 128 + nt * 16 + lm;   // this lane's h (B n-index & C col)
            const unsigned short* wrow = w1tt + (size_t)h * D + q * 8;
            f32x4 acc = (f32x4){0.f, 0.f, 0.f, 0.f};
#pragma unroll
            for (int kk = 0; kk < 4; ++kk) {
                const bf16x8 bF = *(const bf16x8*)(wrow + kk * 32);
                acc = __builtin_amdgcn_mfma_f32_16x16x32_bf16(aF[kk], bF, acc, 0, 0, 0);
            }
            const float w2v = w2L[h];
            const float4 p0 = *(const float4*)(&phT[h][0]);
            const float4 p1 = *(const float4*)(&phT[h][4]);
            const float phv[8] = {p0.x, p0.y, p0.z, p0.w, p1.x, p1.y, p1.z, p1.w};
#pragma unroll
            for (int b = 0; b < NB; ++b)
#pragma unroll
                for (int r = 0; r < 4; ++r)
                    spart[b * 4 + r] += fmaxf(phv[b] + acc[r], 0.f) * w2v;
        }
    }

    // reduce over the 16 lm lanes (bits 0..3 of lane)
#pragma unroll
    for (int m = 1; m <= 8; m <<= 1) {
#pragma unroll
        for (int i = 0; i < NB * 4; ++i)
            spart[i] += __shfl_xor(spart[i], m, 64);
    }
    if (lm == 0) {
#pragma unroll
        for (int r = 0; r < 4; ++r) {
            const int e = base_e + m0 + q * 4 + r;
            if (e < E) {
#pragma unroll
                for (int b = 0; b < NB; ++b)
                    scores[(size_t)b * E + e] = spart[b * 4 + r];
            }
        }
    }
}

// ---------------------------------------------------------------------------
// K3: shard top-16 (bf16-approx scores). 64 blocks = 8 rows x 8 shards.
// Shards are disjoint -> the 128 candidates per row are unique indices, and
// every row-top-16 element is within its shard's top-16 (superset guarantee).
// ---------------------------------------------------------------------------
__global__ __launch_bounds__(256) void topk_shard_kernel(
        const float* __restrict__ scores, int E,
        unsigned long long* __restrict__ cand) {
    const int b = blockIdx.x >> 3;
    const int s = blockIdx.x & 7;
    const int tid = threadIdx.x;
    const int lane = tid & 63;
    const int wave = tid >> 6;
    const int shard = (E + NSHARD - 1) / NSHARD;
    const int start = s * shard;
    const int end = min(E, start + shard);
    const float* row = scores + (size_t)b * E;

    unsigned long long keys[CPS];
#pragma unroll
    for (int i = 0; i < CPS; ++i) keys[i] = 0ull;

    for (int e = start + tid; e < end; e += 256) {
        unsigned long long key = sk_encode(row[e], e);
        if (key > keys[CPS - 1]) {
#pragma unroll
            for (int j = 0; j < CPS; ++j) {
                const bool gt = key > keys[j];
                const unsigned long long mx = gt ? key : keys[j];
                key = gt ? keys[j] : key;
                keys[j] = mx;
            }
        }
    }

    __shared__ unsigned long long cl[4 * CPS];   // 64 entries
    for (int r = 0; r < CPS; ++r) {
        const unsigned long long m = wave_max64(keys[0]);
        if (keys[0] == m) {
#pragma unroll
            for (int j = 0; j < CPS - 1; ++j) keys[j] = keys[j + 1];
            keys[CPS - 1] = 0ull;
        }
        if (lane == 0) cl[wave * CPS + r] = m;
    }
    __syncthreads();
    if (wave == 0) {
        unsigned long long v = cl[lane];          // exactly 64 candidates
        for (int r = 0; r < CPS; ++r) {
            const unsigned long long m = wave_max64(v);
            if (v == m) v = 0ull;
            if (lane == 0) cand[(size_t)(b * NSHARD + s) * CPS + r] = m;
        }
    }
}

// ---------------------------------------------------------------------------
// K4: exact fp32 rescore, 4 candidates per block, 256 blocks.
// ---------------------------------------------------------------------------
__global__ __launch_bounds__(HDIM) void rescore_kernel(
        const unsigned long long* __restrict__ cand,
        const float* __restrict__ ent_emb, const float* __restrict__ W1,
        const float* __restrict__ ph, const float* __restrict__ W2,
        const float* __restrict__ b2, float* __restrict__ exact) {
    const int b = blockIdx.x >> 5;          // 32 blocks per row
    const int cg = blockIdx.x & 31;
    const int tid = threadIdx.x;
    const int lane = tid & 63;
    const int wave = tid >> 6;

    __shared__ float entR[RCPB][D];         // 2 KB
    __shared__ int eIdx[RCPB];
    if (tid < RCPB)
        eIdx[tid] = sk_idx(cand[(size_t)b * NCAND + cg * RCPB + tid]);
    __syncthreads();
    if (tid < RCPB * (D / 4)) {
        const int row = tid >> 5, c4 = (tid & 31) * 4;
        *(float4*)(&entR[row][c4]) =
            *(const float4*)(ent_emb + (size_t)eIdx[row] * D + c4);
    }
    __syncthreads();

    const float* w1t = W1 + 2 * D * HDIM;
    float acc[RCPB] = {0.f, 0.f, 0.f, 0.f};
#pragma unroll 4
    for (int d = 0; d < D; ++d) {
        const float w = w1t[d * HDIM + tid];   // coalesced; entR reads broadcast
#pragma unroll
        for (int c = 0; c < RCPB; ++c) acc[c] += entR[c][d] * w;
    }
    const float phv = ph[b * HDIM + tid];
    const float w2v = W2[tid];
    float s[RCPB];
#pragma unroll
    for (int c = 0; c < RCPB; ++c) s[c] = fmaxf(acc[c] + phv, 0.f) * w2v;

#pragma unroll
    for (int m = 1; m <= 32; m <<= 1)
#pragma unroll
        for (int c = 0; c < RCPB; ++c) s[c] += __shfl_xor(s[c], m, 64);

    __shared__ float red[4][RCPB];
    if (lane == 0)
#pragma unroll
        for (int c = 0; c < RCPB; ++c) red[wave][c] = s[c];
    __syncthreads();
    if (tid < RCPB)
        exact[(size_t)b * NCAND + cg * RCPB + tid] =
            red[0][tid] + red[1][tid] + red[2][tid] + red[3][tid] + b2[0];
}

// ---------------------------------------------------------------------------
// K5: final top-k per row from 128 exactly-scored candidates. 1 block.
// ---------------------------------------------------------------------------
__global__ __launch_bounds__(NB * 64) void final_kernel(
        const unsigned long long* __restrict__ cand,
        const float* __restrict__ exact, int k,
        float* __restrict__ out_idx, float* __restrict__ out_val) {
    const int b = threadIdx.x >> 6;     // wave = row
    const int lane = threadIdx.x & 63;

    unsigned long long k0, k1;
    {
        const int c0 = lane, c1 = lane + 64;
        const unsigned long long a = sk_encode(exact[b * NCAND + c0],
                                               sk_idx(cand[b * NCAND + c0]));
        const unsigned long long bb = sk_encode(exact[b * NCAND + c1],
                                                sk_idx(cand[b * NCAND + c1]));
        k0 = a > bb ? a : bb;
        k1 = a > bb ? bb : a;
    }
    for (int r = 0; r < k; ++r) {
        const unsigned long long m = wave_max64(k0);
        if (k0 == m) { k0 = k1; k1 = 0ull; }
        if (lane == 0) {
            out_idx[b * k + r] = (float)sk_idx(m);
            out_val[b * k + r] = sk_val(m);
        }
    }
}

// ---------------------------------------------------------------------------
extern "C" void kernel_launch(void* const* d_in, const int* in_sizes, int n_in,
                              void* d_out, int out_size, void* d_ws, size_t ws_size,
                              hipStream_t stream) {
    const int*   head     = (const int*)d_in[0];
    const int*   relation = (const int*)d_in[1];
    const float* ent_emb  = (const float*)d_in[3];
    const float* rel_emb  = (const float*)d_in[4];
    const float* W1       = (const float*)d_in[5];
    const float* b1       = (const float*)d_in[6];
    const float* W2       = (const float*)d_in[7];
    const float* b2       = (const float*)d_in[8];

    const int B = in_sizes[0];          // 8
    const int E = in_sizes[3] / D;      // 50000
    int k = out_size / (2 * B);         // 10
    if (k > CPS) k = CPS;

    char* ws = (char*)d_ws;
    unsigned long long* cand  = (unsigned long long*)ws;            //  8 KB
    float*          ph        = (float*)(ws + 8192);                //  8 KB
    unsigned short* w1tt      = (unsigned short*)(ws + 16384);      // 64 KB
    float*          exact     = (float*)(ws + 81920);               //  4 KB
    float*          scores    = (float*)(ws + 86016);               // 1.6 MB
    float*          out       = (float*)d_out;

    prep_kernel<<<NB + 8, HDIM, 0, stream>>>(head, relation, ent_emb, rel_emb,
                                             W1, b1, ph, w1tt);
    const int nblk = (E + EPB - 1) / EPB;
    score_kernel<<<nblk, 256, 0, stream>>>(ent_emb, w1tt, ph, W2, scores, E);
    topk_shard_kernel<<<NB * NSHARD, 256, 0, stream>>>(scores, E, cand);
    rescore_kernel<<<NB * (NCAND / RCPB), HDIM, 0, stream>>>(cand, ent_emb, W1,
                                                             ph, W2, b2, exact);
    final_kernel<<<1, NB * 64, 0, stream>>>(cand, exact, k, out, out + (size_t)B * k);
}